// Round 5
// baseline (149.798 us; speedup 1.0000x reference)
//
#include <hip/hip_runtime.h>

// Problem constants: N=4, C=H=W=32, grid 33^3
#define VG     35937     // 33^3 vertices per batch
#define NF4    393216    // float4s per F-length chunk (F = 1572864 faces)

// Output offsets (in floats), concatenated in reference return order
#define O_VC   0          // vert_counts (4)
#define O_FC   4          // face_counts (4)
#define O_VP   8          // vpos_masked (143748*3)
#define O_US   431252     // used (143748)
#define O_EI   575000     // edge_index (2*6*F = 18874368)
#define O_FA   19449368   // faces (F*3 = 4718592)
#define O_FM   24167960   // face_mask (F = 1572864)
#define O_EM   25740824   // edge_mask (6F = 9437184)

// float4-unit bases of the big regions
#define F4_EI  143750     // O_EI/4
#define F4_FA  4862342    // O_FA/4
#define F4_FM  6041990    // O_FM/4
#define F4_EM  6435206    // O_EM/4

// grid-stride space: EI (4718592 f4) ++ FA (1179648 f4) ++ EM (2359296 f4)
#define GS_EI_END  4718592u
#define GS_FA_END  5898240u
#define GS_TOT     8257536u

#define BPB    141        // vertex blocks per batch (ceil(35937/256))
#define NVB    (4 * BPB)  // 564 vertex blocks
#define NFMB   1536       // face_mask blocks (one float4/thread + counts)
#define NGS    4096       // grid-stride worker blocks for EI/FA/EM
#define B_FM   NVB
#define B_GS   (B_FM + NFMB)      // 2100
#define NBLK   (B_GS + NGS)       // 6196

// counts workspace (round-2 proven scheme)
#define NQB    1536               // face-count partial slots
#define NPART  (NQB + NVB)        // 2100 partials in d_ws

// decode pair t -> voxel v, face-pair fp (0:z 1:y 2:x)
__device__ __forceinline__ void pair_decode(unsigned t, int& v, int& fp) {
  unsigned uv = t / 3u;
  fp = (int)(t - 3u * uv);
  v = (int)uv;
}

// corner-id offsets relative to base, selected by fp (branchless cndmask)
struct Corners { int a0,a1,a2,a3,b0,b1,b2,b3; };
__device__ __forceinline__ Corners corner_offs(int fp) {
  Corners c;
  c.a0 = fp==0 ? 0    : 1089;
  c.a1 = fp==0 ? 1    : (fp==1 ? 1090 : 0);
  c.a2 = fp==0 ? 33   : (fp==1 ? 0    : 1122);
  c.a3 = fp==0 ? 34   : (fp==1 ? 1    : 33);
  c.b0 = fp==0 ? 1089 : (fp==1 ? 33   : 1);
  c.b1 = fp==1 ? 34   : 1090;
  c.b2 = fp==2 ? 34   : 1122;
  c.b3 = 1123;
  return c;
}

// exposure masks for pair t (3 L2-resident loads, proven r0-r4 code)
__device__ __forceinline__ float2 pair_mask(const float* __restrict__ probas,
                                            int v, int fp) {
  int x = v & 31, y = (v >> 5) & 31, z = (v >> 10) & 31;
  float m0 = 0.0f, m1 = 0.0f;
  if (probas[v] > 0.5f) {
    bool nm, np;
    if (fp == 0)      { nm = (z > 0)  && probas[v - 1024] > 0.5f;
                        np = (z < 31) && probas[v + 1024] > 0.5f; }
    else if (fp == 1) { nm = (y > 0)  && probas[v - 32]   > 0.5f;
                        np = (y < 31) && probas[v + 32]   > 0.5f; }
    else              { nm = (x > 0)  && probas[v - 1]    > 0.5f;
                        np = (x < 31) && probas[v + 1]    > 0.5f; }
    m0 = nm ? 0.0f : 1.0f;
    m1 = np ? 0.0f : 1.0f;
  }
  return make_float2(m0, m1);
}

__device__ __forceinline__ int pair_base(int v) {
  int x = v & 31, y = (v >> 5) & 31, z = (v >> 10) & 31, n = v >> 15;
  return n * VG + (z * 33 + y) * 33 + x;
}

// MODE 0: count partials -> d_ws (reduced by counts_reduce). MODE 1: atomicAdd.
template <int MODE>
__global__ __launch_bounds__(256) void cubify_main(
    const float* __restrict__ probas, float* __restrict__ out,
    float* __restrict__ ws) {
  __shared__ int wsum[4];
  int tid = threadIdx.x;
  int lane = tid & 63, wid = tid >> 6;
  int b = blockIdx.x;

  if (b < NVB) {
    // -------- vertex path: used, vpos_masked, vert_count partials ----------
    int n  = b / BPB;
    int li = (b - n * BPB) * 256 + tid;
    int u = 0;
    if (li < VG) {
      int gz = li / 1089;
      int r  = li - gz * 1089;
      int gy = r / 33;
      int gx = r - gy * 33;
      bool any_occ = false, all_occ = true;
      #pragma unroll
      for (int dz = 0; dz < 2; ++dz)
        #pragma unroll
        for (int dy = 0; dy < 2; ++dy)
          #pragma unroll
          for (int dx = 0; dx < 2; ++dx) {
            int z = gz - dz, y = gy - dy, x = gx - dx;
            if (z >= 0 && z < 32 && y >= 0 && y < 32 && x >= 0 && x < 32) {
              bool o = probas[((n * 32 + z) * 32 + y) * 32 + x] > 0.5f;
              any_occ |= o; all_occ &= o;
            } else {
              all_occ = false;
            }
          }
      u = (any_occ && !all_occ) ? 1 : 0;

      int idx = n * VG + li;
      out[O_US + idx] = u ? 1.0f : 0.0f;
      float* vp = out + O_VP + 3 * idx;
      if (u) {
        vp[0] = (float)gz - 0.5f;
        vp[1] = (float)gy - 0.5f;
        vp[2] = (float)gx - 0.5f;
      } else {
        vp[0] = 0.0f; vp[1] = 0.0f; vp[2] = 0.0f;
      }
    }
    int cnt = u;
    for (int d = 32; d > 0; d >>= 1) cnt += __shfl_down(cnt, d, 64);
    if (lane == 0) wsum[wid] = cnt;
    __syncthreads();
    if (tid == 0) {
      float s = (float)(wsum[0] + wsum[1] + wsum[2] + wsum[3]);
      if (MODE == 0) ws[NQB + b] = s;
      else atomicAdd(&out[O_VC + n], s);
    }
  } else if (b < B_GS) {
    // -------- face_mask: one float4 per thread + face_count partials -------
    int qb = b - B_FM;
    unsigned t = (unsigned)qb * 256u + tid;
    int v, fp; pair_decode(t, v, fp);
    float2 m = pair_mask(probas, v, fp);
    ((float4*)out)[F4_FM + t] = make_float4(m.x, m.x, m.y, m.y);

    int cnt = 2 * ((m.x > 0.0f) + (m.y > 0.0f));
    for (int d = 32; d > 0; d >>= 1) cnt += __shfl_down(cnt, d, 64);
    if (lane == 0) wsum[wid] = cnt;
    __syncthreads();
    if (tid == 0) {
      float s = (float)(wsum[0] + wsum[1] + wsum[2] + wsum[3]);
      if (MODE == 0) ws[qb] = s;
      else atomicAdd(&out[O_FC + (v >> 15)], s);  // n uniform per block
    }
  } else {
    // -------- grid-stride workers: EI ++ FA ++ EM, fill-like sweep ---------
    // Persistent waves, stores fire-and-forget (deep pipelining, no per-4KB
    // block launch — the two properties the fill has and rounds 2/4 lacked).
    float4* o4 = (float4*)out;
    for (unsigned i = (unsigned)(b - B_GS) * 256u + tid; i < GS_TOT;
         i += (unsigned)NGS * 256u) {
      float4 val;
      unsigned g;
      if (i < GS_EI_END) {
        // edge_index: 12 F4-chunks, column pattern [A,B,A,B,C,C,B,C,C,A,B,A]
        unsigned e = i;
        unsigned ch = e / (unsigned)NF4;          // 0..11 (wave-uniform a.e.)
        unsigned t = e - ch * (unsigned)NF4;      // pair index
        int v, fp; pair_decode(t, v, fp);
        int base = pair_base(v);
        Corners c = corner_offs(fp);
        const unsigned pat = (0u<<0)|(1u<<2)|(0u<<4)|(1u<<6)|(2u<<8)|(2u<<10)|
                             (1u<<12)|(2u<<14)|(2u<<16)|(0u<<18)|(1u<<20)|(0u<<22);
        int sel = (pat >> (2 * ch)) & 3;
        if (sel == 0)      val = make_float4((float)(base + c.a0), (float)(base + c.a1),
                                             (float)(base + c.b0), (float)(base + c.b1));
        else if (sel == 1) val = make_float4((float)(base + c.a1), (float)(base + c.a2),
                                             (float)(base + c.b1), (float)(base + c.b2));
        else               val = make_float4((float)(base + c.a2), (float)(base + c.a3),
                                             (float)(base + c.b2), (float)(base + c.b3));
        g = F4_EI + e;
      } else if (i < GS_FA_END) {
        // faces: floats [12t,12t+12) = [a0,a1,a2, a1,a2,a3, b0,b1,b2, b1,b2,b3]
        unsigned e = i - GS_EI_END;
        unsigned t = e / 3u;
        int r = (int)(e - 3u * t);
        int v, fp; pair_decode(t, v, fp);
        int base = pair_base(v);
        Corners c = corner_offs(fp);
        int w0 = r==0 ? c.a0 : (r==1 ? c.a2 : c.b2);
        int w1 = r==0 ? c.a1 : (r==1 ? c.a3 : c.b1);
        int w2 = r==0 ? c.a2 : (r==1 ? c.b0 : c.b2);
        int w3 = r==0 ? c.a1 : (r==1 ? c.b1 : c.b3);
        val = make_float4((float)(base + w0), (float)(base + w1),
                          (float)(base + w2), (float)(base + w3));
        g = F4_FA + e;
      } else {
        // edge_mask = tile(face_mask, 6)
        unsigned e = i - GS_FA_END;
        unsigned ch = e / (unsigned)NF4;          // 0..5
        unsigned t = e - ch * (unsigned)NF4;
        int v, fp; pair_decode(t, v, fp);
        float2 m = pair_mask(probas, v, fp);
        val = make_float4(m.x, m.x, m.y, m.y);
        g = F4_EM + e;
      }
      o4[g] = val;
    }
  }
}

// One wave per output scalar (round-2 proven). Sole writer of out[0..8).
__global__ __launch_bounds__(512) void counts_reduce(
    const float* __restrict__ ws, float* __restrict__ out) {
  int w = threadIdx.x >> 6, lane = threadIdx.x & 63;
  float s = 0.0f;
  if (w < 4) {
    for (int i = lane; i < BPB; i += 64) s += ws[NQB + w * BPB + i];
  } else {
    int n = w - 4;
    for (int i = lane; i < 384; i += 64) s += ws[n * 384 + i];
  }
  for (int d = 32; d > 0; d >>= 1) s += __shfl_down(s, d, 64);
  if (lane == 0) out[w] = s;   // out[0..3]=vert_counts, out[4..7]=face_counts
}

extern "C" void kernel_launch(void* const* d_in, const int* in_sizes, int n_in,
                              void* d_out, int out_size, void* d_ws, size_t ws_size,
                              hipStream_t stream) {
  const float* probas = (const float*)d_in[0];
  float* out = (float*)d_out;
  float* ws = (float*)d_ws;
  if (ws != nullptr && ws_size >= NPART * sizeof(float)) {
    cubify_main<0><<<NBLK, 256, 0, stream>>>(probas, out, ws);
    counts_reduce<<<1, 512, 0, stream>>>(ws, out);
  } else {
    cubify_main<1><<<NBLK, 256, 0, stream>>>(probas, out, ws);
  }
}